// Round 12
// baseline (673.433 us; speedup 1.0000x reference)
//
#include <hip/hip_runtime.h>

typedef unsigned short u16;
typedef unsigned int u32;
typedef __bf16 bf16_t;
typedef bf16_t bf16x8 __attribute__((ext_vector_type(8)));
typedef bf16_t bf16x4_t __attribute__((ext_vector_type(4)));
typedef float f32x4 __attribute__((ext_vector_type(4)));
typedef unsigned short ushort8_t __attribute__((ext_vector_type(8)));

#define S_LEN 2048
#define DM 1024
#define NH 16
#define HDIM 64
#define PSTR 80   // attn P row stride in u16
#define TSTR 136  // epilogue-transpose LDS row stride in u16

// ---- helpers ----
__device__ __forceinline__ u16 f2b(float f) {
  u32 u = __builtin_bit_cast(u32, f);
  u32 r = (u + 0x7FFFu + ((u >> 16) & 1u)) >> 16;  // RNE
  return (u16)r;
}

__device__ __forceinline__ void gload16(const void* g, void* l) {
  __builtin_amdgcn_global_load_lds((const __attribute__((address_space(1))) void*)g,
                                   (__attribute__((address_space(3))) void*)l,
                                   16, 0, 0);
}

__device__ __forceinline__ bf16x8 ld_bf8(const u16* p) {
  return *reinterpret_cast<const bf16x8*>(p);
}

// ---- 64x64 tile staging for attn (row stride `stride` u16), source-swizzled
// (load-bearing there: 128B rows -> 16-way conflict without it) ----
__device__ __forceinline__ void stage_tile256(const u16* __restrict__ base, int stride,
                                              u16* __restrict__ dst, int tid) {
#pragma unroll
  for (int i = 0; i < 2; ++i) {
    int ci = i * 256 + tid;
    int row = ci >> 3, col = ci & 7;
    gload16(base + (size_t)row * stride + ((col ^ (row & 7)) << 3), dst + ci * 8);
  }
}
__device__ __forceinline__ bf16x8 ld_swz64(const u16* lds, int row, int chunk) {
  return ld_bf8(lds + row * 64 + ((chunk ^ (row & 7)) << 3));
}

// ---- kernel 1: x f32 -> bf16 ----
__global__ __launch_bounds__(256) void k_cvt(const float* __restrict__ in, u16* __restrict__ out) {
  int i = (blockIdx.x * 256 + threadIdx.x) * 4;
  float4 v = *reinterpret_cast<const float4*>(in + i);
  ushort4 o = make_ushort4(f2b(v.x), f2b(v.y), f2b(v.z), f2b(v.w));
  *reinterpret_cast<ushort4*>(out + i) = o;
}

// ---- kernel 2: all three W [K][N] f32 -> Wt [3*N][K] bf16 in one launch ----
__global__ __launch_bounds__(256) void k_wt3(const float* __restrict__ Wq, const float* __restrict__ Wk,
                                             const float* __restrict__ Wv, u16* __restrict__ Wt) {
  __shared__ float t[32][33];
  const float* W = (blockIdx.z == 0) ? Wq : (blockIdx.z == 1) ? Wk : Wv;
  u16* dst = Wt + (size_t)blockIdx.z * (DM * DM);
  int n0 = blockIdx.x * 32, k0 = blockIdx.y * 32;
  int tx = threadIdx.x & 31, ty = threadIdx.x >> 5;
#pragma unroll
  for (int i = 0; i < 32; i += 8)
    t[ty + i][tx] = W[(size_t)(k0 + ty + i) * DM + n0 + tx];
  __syncthreads();
#pragma unroll
  for (int i = 0; i < 32; i += 8)
    dst[(size_t)(n0 + ty + i) * DM + k0 + tx] = f2b(t[tx][ty + i]);
}

// ---- GEMM core: 32 K-iters, linear LDS staging, single buffer.
// TRANSPOSED: mfma(bfr, af) so thread's 4 accs contiguous in n. ----
template <bool TRANSPOSED>
__device__ __forceinline__ void gemm_loop(const u16* __restrict__ Ag, const u16* __restrict__ Bg,
                                          u16* __restrict__ At, u16* __restrict__ Bt,
                                          f32x4 (&acc)[4][4], int tid, int l15, int lg,
                                          int wm, int wn) {
  for (int kt = 0; kt < 32; ++kt) {
    int kk = kt * 32;
#pragma unroll
    for (int i = 0; i < 2; ++i) {
      int t2 = i * 256 + tid;
      int row = t2 >> 2, c = t2 & 3;
      gload16(Ag + (size_t)row * DM + kk + c * 8, At + t2 * 8);
      gload16(Bg + (size_t)row * DM + kk + c * 8, Bt + t2 * 8);
    }
    __syncthreads();
    bf16x8 af[4], bfr[4];
#pragma unroll
    for (int mi = 0; mi < 4; ++mi)
      af[mi] = ld_bf8(At + (wm * 64 + mi * 16 + l15) * 32 + lg * 8);
#pragma unroll
    for (int ni = 0; ni < 4; ++ni)
      bfr[ni] = ld_bf8(Bt + (wn * 64 + ni * 16 + l15) * 32 + lg * 8);
#pragma unroll
    for (int mi = 0; mi < 4; ++mi)
#pragma unroll
      for (int ni = 0; ni < 4; ++ni) {
        if (TRANSPOSED)
          acc[mi][ni] = __builtin_amdgcn_mfma_f32_16x16x32_bf16(bfr[ni], af[mi], acc[mi][ni], 0, 0, 0);
        else
          acc[mi][ni] = __builtin_amdgcn_mfma_f32_16x16x32_bf16(af[mi], bfr[ni], acc[mi][ni], 0, 0, 0);
      }
    __syncthreads();
  }
}

// ---- kernel 3: fused QKV GEMM, 128x128 tile, BK=32, 4 waves, 2D natural grid.
// LDS halved to 17.4 KB (two-pass 64-row epilogue) + __launch_bounds__(256,8):
// occupancy ceiling 4 -> 8 blocks/CU (grid gives 6). Latency-bound loop ->
// resident waves are the throughput knob (R11: 3 waves/SIMD beat all schedule
// variants). Q/K: C^T in regs -> LDS transpose -> coalesced [s][hd] stores.
// V: C -> LDS transpose -> V^T [bh][hd][s]. ----
__global__ __launch_bounds__(256, 8) void k_gemm(const u16* __restrict__ Xb, const u16* __restrict__ Wt_all,
                                                 u16* __restrict__ Out_all, u16* __restrict__ Vt,
                                                 float qscale) {
  __shared__ __attribute__((aligned(16))) u16 smem[64 * TSTR];  // 17.4 KB (staging 16 KB / T 17.4 KB)
  u16* At = smem;          // 128x32
  u16* Bt = smem + 4096;   // 128x32
  int bx = blockIdx.x, by = blockIdx.y;
  int n0g = bx * 128, m0 = by * 128;
  int which = n0g >> 10;              // uniform per block (128 | 1024)
  int n0 = n0g & 1023;
  int tid = threadIdx.x;
  int lane = tid & 63, w = tid >> 6;
  int l15 = lane & 15, lg = lane >> 4;
  int wm = w >> 1, wn = w & 1;        // 2x2 waves, wave tile 64x64

  const u16* Ag = Xb + (size_t)m0 * DM;
  const u16* Bg = Wt_all + (size_t)n0g * DM;

  f32x4 acc[4][4] = {};
  u16* T = smem;
  int b = m0 >> 11, s0 = m0 & 2047;
  int base_h = n0 >> 6;

  if (which < 2) {
    gemm_loop<true>(Ag, Bg, At, Bt, acc, tid, l15, lg, wm, wn);
    // Q/K epilogue, two 64-row halves (rows = m_local): waves wm==hf write
    float scale = (which == 0) ? qscale : 1.0f;
    u16* Out = Out_all + (size_t)which * (size_t)(4 * NH * S_LEN * HDIM);
#pragma unroll
    for (int hf = 0; hf < 2; ++hf) {
      if (wm == hf) {
#pragma unroll
        for (int mi = 0; mi < 4; ++mi)
#pragma unroll
          for (int ni = 0; ni < 4; ++ni) {
            ushort4 w4 = make_ushort4(f2b(acc[mi][ni][0] * scale), f2b(acc[mi][ni][1] * scale),
                                      f2b(acc[mi][ni][2] * scale), f2b(acc[mi][ni][3] * scale));
            *reinterpret_cast<ushort4*>(T + (mi * 16 + l15) * TSTR +
                                        wn * 64 + ni * 16 + lg * 4) = w4;
          }
      }
      __syncthreads();
#pragma unroll
      for (int pass = 0; pass < 4; ++pass) {
        int row = pass * 16 + (tid >> 4);     // m_local within half (s offset)
        int col = (tid & 15) * 8;             // n_local chunk (within one head)
        ushort8_t v = *reinterpret_cast<const ushort8_t*>(T + row * TSTR + col);
        int h = base_h + (col >> 6), hd = col & 63;
        *reinterpret_cast<ushort8_t*>(
            Out + ((size_t)(b * NH + h) * S_LEN + s0 + hf * 64 + row) * HDIM + hd) = v;
      }
      if (hf == 0) __syncthreads();
    }
  } else {
    gemm_loop<false>(Ag, Bg, At, Bt, acc, tid, l15, lg, wm, wn);
    // V epilogue, two 64-row halves (rows = n_local): waves wn==hf write
#pragma unroll
    for (int hf = 0; hf < 2; ++hf) {
      if (wn == hf) {
#pragma unroll
        for (int mi = 0; mi < 4; ++mi)
#pragma unroll
          for (int ni = 0; ni < 4; ++ni) {
            ushort4 w4 = make_ushort4(f2b(acc[mi][ni][0]), f2b(acc[mi][ni][1]),
                                      f2b(acc[mi][ni][2]), f2b(acc[mi][ni][3]));
            *reinterpret_cast<ushort4*>(T + (ni * 16 + l15) * TSTR +
                                        wm * 64 + mi * 16 + lg * 4) = w4;
          }
      }
      __syncthreads();
#pragma unroll
      for (int pass = 0; pass < 4; ++pass) {
        int row = pass * 16 + (tid >> 4);     // n_local within half (hd)
        int col = (tid & 15) * 8;             // m_local chunk (s offset)
        ushort8_t v = *reinterpret_cast<const ushort8_t*>(T + row * TSTR + col);
        int ng = hf * 64 + row;
        int h = base_h + (ng >> 6), hd = ng & 63;
        *reinterpret_cast<ushort8_t*>(
            Vt + ((size_t)((b * NH + h) * HDIM + hd)) * S_LEN + s0 + col) = v;
      }
      if (hf == 0) __syncthreads();
    }
  }
}

// ---- block-cooperative flash strip: 4 waves, same head, lockstep K-tiles.
// K double-buffered (staged 1 ahead), V single-buffered. Counted waits only.
// Static-exponent softmax: p = exp2(s) raw (normalization cancels in o/ls). ----
__device__ __forceinline__ void attn_strip(const u16* __restrict__ Qp, const u16* __restrict__ Kp,
                                           const u16* __restrict__ Vp, float* __restrict__ out,
                                           int b, int h, int qbase, int w, int tid, int lane, int nt,
                                           u16 (*Kd)[64 * 64], u16* __restrict__ Vd,
                                           u16* __restrict__ Pw) {
  int l15 = lane & 15, lg = lane >> 4;
  int qrow = qbase + w * 16;
  bf16x8 qf0 = ld_bf8(Qp + (size_t)(qrow + l15) * HDIM + lg * 8);
  bf16x8 qf1 = ld_bf8(Qp + (size_t)(qrow + l15) * HDIM + 32 + lg * 8);
  f32x4 o[4] = {};
  float ls = 0.f;
  int qa = qrow + l15;

  stage_tile256(Kp, HDIM, Kd[0], tid);
  asm volatile("s_waitcnt vmcnt(0)" ::: "memory");
  __builtin_amdgcn_sched_barrier(0);
  __builtin_amdgcn_s_barrier();
  __builtin_amdgcn_sched_barrier(0);

  for (int kt = 0; kt < nt; ++kt) {
    int k0 = kt * 64;
    int cur = kt & 1;
    bool pre = (kt + 1 < nt);
    stage_tile256(Vp + k0, S_LEN, Vd, tid);
    if (pre) stage_tile256(Kp + (size_t)(k0 + 64) * HDIM, HDIM, Kd[cur ^ 1], tid);

    if (pre) asm volatile("s_waitcnt vmcnt(4)" ::: "memory");
    else     asm volatile("s_waitcnt vmcnt(2)" ::: "memory");
    __builtin_amdgcn_sched_barrier(0);
    __builtin_amdgcn_s_barrier();
    __builtin_amdgcn_sched_barrier(0);

    f32x4 sc[4];
    __builtin_amdgcn_s_setprio(1);
#pragma unroll
    for (int kb = 0; kb < 4; ++kb) {
      bf16x8 kf0 = ld_swz64(Kd[cur], kb * 16 + l15, lg);
      bf16x8 kf1 = ld_swz64(Kd[cur], kb * 16 + l15, 4 + lg);
      f32x4 z = {};
      z = __builtin_amdgcn_mfma_f32_16x16x32_bf16(kf0, qf0, z, 0, 0, 0);
      sc[kb] = __builtin_amdgcn_mfma_f32_16x16x32_bf16(kf1, qf1, sc[kb] = z, 0, 0, 0);
    }
    __builtin_amdgcn_s_setprio(0);

    if (kt == nt - 1) {
#pragma unroll
      for (int kb = 0; kb < 4; ++kb) {
        bf16x4_t pw;
#pragma unroll
        for (int r = 0; r < 4; ++r) {
          int key = k0 + kb * 16 + lg * 4 + r;
          float e = __builtin_amdgcn_exp2f(sc[kb][r]);
          e = (key > qa) ? 0.f : e;
          ls += e;
          pw[r] = (bf16_t)e;
        }
        *reinterpret_cast<bf16x4_t*>(Pw + l15 * PSTR + kb * 16 + lg * 4) = pw;
      }
    } else {
#pragma unroll
      for (int kb = 0; kb < 4; ++kb) {
        bf16x4_t pw;
#pragma unroll
        for (int r = 0; r < 4; ++r) {
          float e = __builtin_amdgcn_exp2f(sc[kb][r]);
          ls += e;
          pw[r] = (bf16_t)e;
        }
        *reinterpret_cast<bf16x4_t*>(Pw + l15 * PSTR + kb * 16 + lg * 4) = pw;
      }
    }
    asm volatile("" ::: "memory");
    bf16x8 pf0 = ld_bf8(Pw + l15 * PSTR + lg * 8);
    bf16x8 pf1 = ld_bf8(Pw + l15 * PSTR + 32 + lg * 8);

    if (pre) asm volatile("s_waitcnt vmcnt(2) lgkmcnt(0)" ::: "memory");
    else     asm volatile("s_waitcnt vmcnt(0) lgkmcnt(0)" ::: "memory");
    __builtin_amdgcn_sched_barrier(0);
    __builtin_amdgcn_s_barrier();
    __builtin_amdgcn_sched_barrier(0);

    __builtin_amdgcn_s_setprio(1);
#pragma unroll
    for (int n = 0; n < 4; ++n) {
      bf16x8 vf0 = ld_swz64(Vd, n * 16 + l15, lg);
      bf16x8 vf1 = ld_swz64(Vd, n * 16 + l15, 4 + lg);
      o[n] = __builtin_amdgcn_mfma_f32_16x16x32_bf16(pf0, vf0, o[n], 0, 0, 0);
      o[n] = __builtin_amdgcn_mfma_f32_16x16x32_bf16(pf1, vf1, o[n], 0, 0, 0);
    }
    __builtin_amdgcn_s_setprio(0);

    __builtin_amdgcn_sched_barrier(0);
    __builtin_amdgcn_s_barrier();
    __builtin_amdgcn_sched_barrier(0);
  }

  ls += __shfl_xor(ls, 16);
  ls += __shfl_xor(ls, 32);
  float l0 = __shfl(ls, lg * 4 + 0);
  float l1 = __shfl(ls, lg * 4 + 1);
  float l2 = __shfl(ls, lg * 4 + 2);
  float l3 = __shfl(ls, lg * 4 + 3);
  float lsr[4] = {l0, l1, l2, l3};
#pragma unroll
  for (int r = 0; r < 4; ++r) {
    float inv = 1.f / lsr[r];
    int row = qrow + lg * 4 + r;
#pragma unroll
    for (int n = 0; n < 4; ++n)
      out[((size_t)b * S_LEN + row) * DM + h * HDIM + n * 16 + l15] = o[n][r] * inv;
  }
}

// ---- kernel 5: causal flash attention ----
__global__ __launch_bounds__(256, 4) void k_attn(const u16* __restrict__ Qb, const u16* __restrict__ Kb,
                                                 const u16* __restrict__ Vtb, float* __restrict__ out) {
  __shared__ u16 Kd[2][64 * 64];
  __shared__ u16 Vd[64 * 64];
  __shared__ u16 Plds[4][16 * PSTR];
  int j = blockIdx.x;
  int m = j >> 3;
  int x = m & 15;
  int bh = (j & 7) + 8 * (m >> 4);
  int tid = threadIdx.x, lane = tid & 63, w = tid >> 6;
  int b = bh >> 4, h = bh & 15;
  const u16* Qp = Qb + (size_t)bh * S_LEN * HDIM;
  const u16* Kp = Kb + (size_t)bh * S_LEN * HDIM;
  const u16* Vp = Vtb + (size_t)bh * HDIM * S_LEN;
  u16* Pw = Plds[w];
  attn_strip(Qp, Kp, Vp, out, b, h, x * 64, w, tid, lane, x + 1, Kd, Vd, Pw);
  attn_strip(Qp, Kp, Vp, out, b, h, (31 - x) * 64, w, tid, lane, 32 - x, Kd, Vd, Pw);
}

extern "C" void kernel_launch(void* const* d_in, const int* in_sizes, int n_in,
                              void* d_out, int out_size, void* d_ws, size_t ws_size,
                              hipStream_t stream) {
  const float* x  = (const float*)d_in[0];
  const float* Wq = (const float*)d_in[1];
  const float* Wk = (const float*)d_in[2];
  const float* Wv = (const float*)d_in[3];
  float* out = (float*)d_out;

  u16* ws  = (u16*)d_ws;
  u16* xb  = ws;                    // 8192*1024
  u16* wqt = xb + 8388608;          // 3 x 1024*1024 contiguous
  u16* Qb  = wqt + 3145728;         // Q,K each [B,H,S,HD]
  u16* Kb  = Qb + 8388608;
  u16* Vtb = Kb + 8388608;          // [B,H,HD,S] written directly by k_gemm

  const float qscale = 0.125f * 1.44269504088896f;  // 1/sqrt(64) * log2(e)

  k_cvt<<<8192, 256, 0, stream>>>(x, xb);
  k_wt3<<<dim3(32, 32, 3), 256, 0, stream>>>(Wq, Wk, Wv, wqt);
  k_gemm<<<dim3(24, 64), 256, 0, stream>>>(xb, wqt, Qb, Vtb, qscale);
  k_attn<<<1024, 256, 0, stream>>>(Qb, Kb, Vtb, out);
}

// Round 13
// 139.340 us; speedup vs baseline: 4.8330x; 4.8330x over previous
//
#include <hip/hip_runtime.h>

typedef unsigned short u16;
typedef unsigned int u32;
typedef __bf16 bf16_t;
typedef bf16_t bf16x8 __attribute__((ext_vector_type(8)));
typedef bf16_t bf16x4_t __attribute__((ext_vector_type(4)));
typedef float f32x4 __attribute__((ext_vector_type(4)));
typedef unsigned short ushort8_t __attribute__((ext_vector_type(8)));

#define S_LEN 2048
#define DM 1024
#define NH 16
#define HDIM 64
#define PSTR 80   // attn P row stride in u16
#define TSTR 136  // epilogue-transpose LDS row stride in u16

// ---- helpers ----
__device__ __forceinline__ u16 f2b(float f) {
  u32 u = __builtin_bit_cast(u32, f);
  u32 r = (u + 0x7FFFu + ((u >> 16) & 1u)) >> 16;  // RNE
  return (u16)r;
}

__device__ __forceinline__ void gload16(const void* g, void* l) {
  __builtin_amdgcn_global_load_lds((const __attribute__((address_space(1))) void*)g,
                                   (__attribute__((address_space(3))) void*)l,
                                   16, 0, 0);
}

__device__ __forceinline__ bf16x8 ld_bf8(const u16* p) {
  return *reinterpret_cast<const bf16x8*>(p);
}

// ---- 64x64 tile staging for attn (row stride `stride` u16), source-swizzled
// (load-bearing there: 128B rows -> 16-way conflict without it) ----
__device__ __forceinline__ void stage_tile256(const u16* __restrict__ base, int stride,
                                              u16* __restrict__ dst, int tid) {
#pragma unroll
  for (int i = 0; i < 2; ++i) {
    int ci = i * 256 + tid;
    int row = ci >> 3, col = ci & 7;
    gload16(base + (size_t)row * stride + ((col ^ (row & 7)) << 3), dst + ci * 8);
  }
}
__device__ __forceinline__ bf16x8 ld_swz64(const u16* lds, int row, int chunk) {
  return ld_bf8(lds + row * 64 + ((chunk ^ (row & 7)) << 3));
}

// ---- kernel 1: x f32 -> bf16 ----
__global__ __launch_bounds__(256) void k_cvt(const float* __restrict__ in, u16* __restrict__ out) {
  int i = (blockIdx.x * 256 + threadIdx.x) * 4;
  float4 v = *reinterpret_cast<const float4*>(in + i);
  ushort4 o = make_ushort4(f2b(v.x), f2b(v.y), f2b(v.z), f2b(v.w));
  *reinterpret_cast<ushort4*>(out + i) = o;
}

// ---- kernel 2: all three W [K][N] f32 -> Wt [3*N][K] bf16 in one launch ----
__global__ __launch_bounds__(256) void k_wt3(const float* __restrict__ Wq, const float* __restrict__ Wk,
                                             const float* __restrict__ Wv, u16* __restrict__ Wt) {
  __shared__ float t[32][33];
  const float* W = (blockIdx.z == 0) ? Wq : (blockIdx.z == 1) ? Wk : Wv;
  u16* dst = Wt + (size_t)blockIdx.z * (DM * DM);
  int n0 = blockIdx.x * 32, k0 = blockIdx.y * 32;
  int tx = threadIdx.x & 31, ty = threadIdx.x >> 5;
#pragma unroll
  for (int i = 0; i < 32; i += 8)
    t[ty + i][tx] = W[(size_t)(k0 + ty + i) * DM + n0 + tx];
  __syncthreads();
#pragma unroll
  for (int i = 0; i < 32; i += 8)
    dst[(size_t)(n0 + ty + i) * DM + k0 + tx] = f2b(t[tx][ty + i]);
}

// ---- GEMM core: 32 K-iters, linear LDS staging, single buffer.
// TRANSPOSED: mfma(bfr, af) so thread's 4 accs contiguous in n. ----
template <bool TRANSPOSED>
__device__ __forceinline__ void gemm_loop(const u16* __restrict__ Ag, const u16* __restrict__ Bg,
                                          u16* __restrict__ At, u16* __restrict__ Bt,
                                          f32x4 (&acc)[4][4], int tid, int l15, int lg,
                                          int wm, int wn) {
  for (int kt = 0; kt < 32; ++kt) {
    int kk = kt * 32;
#pragma unroll
    for (int i = 0; i < 2; ++i) {
      int t2 = i * 256 + tid;
      int row = t2 >> 2, c = t2 & 3;
      gload16(Ag + (size_t)row * DM + kk + c * 8, At + t2 * 8);
      gload16(Bg + (size_t)row * DM + kk + c * 8, Bt + t2 * 8);
    }
    __syncthreads();
    bf16x8 af[4], bfr[4];
#pragma unroll
    for (int mi = 0; mi < 4; ++mi)
      af[mi] = ld_bf8(At + (wm * 64 + mi * 16 + l15) * 32 + lg * 8);
#pragma unroll
    for (int ni = 0; ni < 4; ++ni)
      bfr[ni] = ld_bf8(Bt + (wn * 64 + ni * 16 + l15) * 32 + lg * 8);
#pragma unroll
    for (int mi = 0; mi < 4; ++mi)
#pragma unroll
      for (int ni = 0; ni < 4; ++ni) {
        if (TRANSPOSED)
          acc[mi][ni] = __builtin_amdgcn_mfma_f32_16x16x32_bf16(bfr[ni], af[mi], acc[mi][ni], 0, 0, 0);
        else
          acc[mi][ni] = __builtin_amdgcn_mfma_f32_16x16x32_bf16(af[mi], bfr[ni], acc[mi][ni], 0, 0, 0);
      }
    __syncthreads();
  }
}

// ---- kernel 3: fused QKV GEMM, 128x128 tile, BK=32, 4 waves, 2D natural grid.
// __launch_bounds__(256,4): 128 regs/wave budget — fits the true live set
// (60 VGPR + 64 AGPR = 124) with NO spills; R12's (256,8) forced 64 regs/wave
// -> acc spilled to scratch (1.8 GB writes, 8x slowdown). 4 waves/SIMD is the
// hard reg ceiling; LDS halved to 17.4 KB so it never binds. ----
__global__ __launch_bounds__(256, 4) void k_gemm(const u16* __restrict__ Xb, const u16* __restrict__ Wt_all,
                                                 u16* __restrict__ Out_all, u16* __restrict__ Vt,
                                                 float qscale) {
  __shared__ __attribute__((aligned(16))) u16 smem[64 * TSTR];  // 17.4 KB
  u16* At = smem;          // 128x32
  u16* Bt = smem + 4096;   // 128x32
  int bx = blockIdx.x, by = blockIdx.y;
  int n0g = bx * 128, m0 = by * 128;
  int which = n0g >> 10;              // uniform per block (128 | 1024)
  int n0 = n0g & 1023;
  int tid = threadIdx.x;
  int lane = tid & 63, w = tid >> 6;
  int l15 = lane & 15, lg = lane >> 4;
  int wm = w >> 1, wn = w & 1;        // 2x2 waves, wave tile 64x64

  const u16* Ag = Xb + (size_t)m0 * DM;
  const u16* Bg = Wt_all + (size_t)n0g * DM;

  f32x4 acc[4][4] = {};
  u16* T = smem;
  int b = m0 >> 11, s0 = m0 & 2047;
  int base_h = n0 >> 6;

  if (which < 2) {
    gemm_loop<true>(Ag, Bg, At, Bt, acc, tid, l15, lg, wm, wn);
    // Q/K epilogue, two 64-row halves (rows = m_local): waves wm==hf write
    float scale = (which == 0) ? qscale : 1.0f;
    u16* Out = Out_all + (size_t)which * (size_t)(4 * NH * S_LEN * HDIM);
#pragma unroll
    for (int hf = 0; hf < 2; ++hf) {
      if (wm == hf) {
#pragma unroll
        for (int mi = 0; mi < 4; ++mi)
#pragma unroll
          for (int ni = 0; ni < 4; ++ni) {
            ushort4 w4 = make_ushort4(f2b(acc[mi][ni][0] * scale), f2b(acc[mi][ni][1] * scale),
                                      f2b(acc[mi][ni][2] * scale), f2b(acc[mi][ni][3] * scale));
            *reinterpret_cast<ushort4*>(T + (mi * 16 + l15) * TSTR +
                                        wn * 64 + ni * 16 + lg * 4) = w4;
          }
      }
      __syncthreads();
#pragma unroll
      for (int pass = 0; pass < 4; ++pass) {
        int row = pass * 16 + (tid >> 4);     // m_local within half (s offset)
        int col = (tid & 15) * 8;             // n_local chunk (within one head)
        ushort8_t v = *reinterpret_cast<const ushort8_t*>(T + row * TSTR + col);
        int h = base_h + (col >> 6), hd = col & 63;
        *reinterpret_cast<ushort8_t*>(
            Out + ((size_t)(b * NH + h) * S_LEN + s0 + hf * 64 + row) * HDIM + hd) = v;
      }
      if (hf == 0) __syncthreads();
    }
  } else {
    gemm_loop<false>(Ag, Bg, At, Bt, acc, tid, l15, lg, wm, wn);
    // V epilogue, two 64-row halves (rows = n_local): waves wn==hf write
#pragma unroll
    for (int hf = 0; hf < 2; ++hf) {
      if (wn == hf) {
#pragma unroll
        for (int mi = 0; mi < 4; ++mi)
#pragma unroll
          for (int ni = 0; ni < 4; ++ni) {
            ushort4 w4 = make_ushort4(f2b(acc[mi][ni][0]), f2b(acc[mi][ni][1]),
                                      f2b(acc[mi][ni][2]), f2b(acc[mi][ni][3]));
            *reinterpret_cast<ushort4*>(T + (ni * 16 + l15) * TSTR +
                                        wm * 64 + mi * 16 + lg * 4) = w4;
          }
      }
      __syncthreads();
#pragma unroll
      for (int pass = 0; pass < 4; ++pass) {
        int row = pass * 16 + (tid >> 4);     // n_local within half (hd)
        int col = (tid & 15) * 8;             // m_local chunk (s offset)
        ushort8_t v = *reinterpret_cast<const ushort8_t*>(T + row * TSTR + col);
        int ng = hf * 64 + row;
        int h = base_h + (ng >> 6), hd = ng & 63;
        *reinterpret_cast<ushort8_t*>(
            Vt + ((size_t)((b * NH + h) * HDIM + hd)) * S_LEN + s0 + col) = v;
      }
      if (hf == 0) __syncthreads();
    }
  }
}

// ---- block-cooperative flash strip: 4 waves, same head, lockstep K-tiles.
// K double-buffered (staged 1 ahead), V single-buffered. Counted waits only.
// Static-exponent softmax: p = exp2(s) raw (normalization cancels in o/ls). ----
__device__ __forceinline__ void attn_strip(const u16* __restrict__ Qp, const u16* __restrict__ Kp,
                                           const u16* __restrict__ Vp, float* __restrict__ out,
                                           int b, int h, int qbase, int w, int tid, int lane, int nt,
                                           u16 (*Kd)[64 * 64], u16* __restrict__ Vd,
                                           u16* __restrict__ Pw) {
  int l15 = lane & 15, lg = lane >> 4;
  int qrow = qbase + w * 16;
  bf16x8 qf0 = ld_bf8(Qp + (size_t)(qrow + l15) * HDIM + lg * 8);
  bf16x8 qf1 = ld_bf8(Qp + (size_t)(qrow + l15) * HDIM + 32 + lg * 8);
  f32x4 o[4] = {};
  float ls = 0.f;
  int qa = qrow + l15;

  stage_tile256(Kp, HDIM, Kd[0], tid);
  asm volatile("s_waitcnt vmcnt(0)" ::: "memory");
  __builtin_amdgcn_sched_barrier(0);
  __builtin_amdgcn_s_barrier();
  __builtin_amdgcn_sched_barrier(0);

  for (int kt = 0; kt < nt; ++kt) {
    int k0 = kt * 64;
    int cur = kt & 1;
    bool pre = (kt + 1 < nt);
    stage_tile256(Vp + k0, S_LEN, Vd, tid);
    if (pre) stage_tile256(Kp + (size_t)(k0 + 64) * HDIM, HDIM, Kd[cur ^ 1], tid);

    if (pre) asm volatile("s_waitcnt vmcnt(4)" ::: "memory");
    else     asm volatile("s_waitcnt vmcnt(2)" ::: "memory");
    __builtin_amdgcn_sched_barrier(0);
    __builtin_amdgcn_s_barrier();
    __builtin_amdgcn_sched_barrier(0);

    f32x4 sc[4];
    __builtin_amdgcn_s_setprio(1);
#pragma unroll
    for (int kb = 0; kb < 4; ++kb) {
      bf16x8 kf0 = ld_swz64(Kd[cur], kb * 16 + l15, lg);
      bf16x8 kf1 = ld_swz64(Kd[cur], kb * 16 + l15, 4 + lg);
      f32x4 z = {};
      z = __builtin_amdgcn_mfma_f32_16x16x32_bf16(kf0, qf0, z, 0, 0, 0);
      sc[kb] = __builtin_amdgcn_mfma_f32_16x16x32_bf16(kf1, qf1, sc[kb] = z, 0, 0, 0);
    }
    __builtin_amdgcn_s_setprio(0);

    if (kt == nt - 1) {
#pragma unroll
      for (int kb = 0; kb < 4; ++kb) {
        bf16x4_t pw;
#pragma unroll
        for (int r = 0; r < 4; ++r) {
          int key = k0 + kb * 16 + lg * 4 + r;
          float e = __builtin_amdgcn_exp2f(sc[kb][r]);
          e = (key > qa) ? 0.f : e;
          ls += e;
          pw[r] = (bf16_t)e;
        }
        *reinterpret_cast<bf16x4_t*>(Pw + l15 * PSTR + kb * 16 + lg * 4) = pw;
      }
    } else {
#pragma unroll
      for (int kb = 0; kb < 4; ++kb) {
        bf16x4_t pw;
#pragma unroll
        for (int r = 0; r < 4; ++r) {
          float e = __builtin_amdgcn_exp2f(sc[kb][r]);
          ls += e;
          pw[r] = (bf16_t)e;
        }
        *reinterpret_cast<bf16x4_t*>(Pw + l15 * PSTR + kb * 16 + lg * 4) = pw;
      }
    }
    asm volatile("" ::: "memory");
    bf16x8 pf0 = ld_bf8(Pw + l15 * PSTR + lg * 8);
    bf16x8 pf1 = ld_bf8(Pw + l15 * PSTR + 32 + lg * 8);

    if (pre) asm volatile("s_waitcnt vmcnt(2) lgkmcnt(0)" ::: "memory");
    else     asm volatile("s_waitcnt vmcnt(0) lgkmcnt(0)" ::: "memory");
    __builtin_amdgcn_sched_barrier(0);
    __builtin_amdgcn_s_barrier();
    __builtin_amdgcn_sched_barrier(0);

    __builtin_amdgcn_s_setprio(1);
#pragma unroll
    for (int n = 0; n < 4; ++n) {
      bf16x8 vf0 = ld_swz64(Vd, n * 16 + l15, lg);
      bf16x8 vf1 = ld_swz64(Vd, n * 16 + l15, 4 + lg);
      o[n] = __builtin_amdgcn_mfma_f32_16x16x32_bf16(pf0, vf0, o[n], 0, 0, 0);
      o[n] = __builtin_amdgcn_mfma_f32_16x16x32_bf16(pf1, vf1, o[n], 0, 0, 0);
    }
    __builtin_amdgcn_s_setprio(0);

    __builtin_amdgcn_sched_barrier(0);
    __builtin_amdgcn_s_barrier();
    __builtin_amdgcn_sched_barrier(0);
  }

  ls += __shfl_xor(ls, 16);
  ls += __shfl_xor(ls, 32);
  float l0 = __shfl(ls, lg * 4 + 0);
  float l1 = __shfl(ls, lg * 4 + 1);
  float l2 = __shfl(ls, lg * 4 + 2);
  float l3 = __shfl(ls, lg * 4 + 3);
  float lsr[4] = {l0, l1, l2, l3};
#pragma unroll
  for (int r = 0; r < 4; ++r) {
    float inv = 1.f / lsr[r];
    int row = qrow + lg * 4 + r;
#pragma unroll
    for (int n = 0; n < 4; ++n)
      out[((size_t)b * S_LEN + row) * DM + h * HDIM + n * 16 + l15] = o[n][r] * inv;
  }
}

// ---- kernel 5: causal flash attention ----
__global__ __launch_bounds__(256, 4) void k_attn(const u16* __restrict__ Qb, const u16* __restrict__ Kb,
                                                 const u16* __restrict__ Vtb, float* __restrict__ out) {
  __shared__ u16 Kd[2][64 * 64];
  __shared__ u16 Vd[64 * 64];
  __shared__ u16 Plds[4][16 * PSTR];
  int j = blockIdx.x;
  int m = j >> 3;
  int x = m & 15;
  int bh = (j & 7) + 8 * (m >> 4);
  int tid = threadIdx.x, lane = tid & 63, w = tid >> 6;
  int b = bh >> 4, h = bh & 15;
  const u16* Qp = Qb + (size_t)bh * S_LEN * HDIM;
  const u16* Kp = Kb + (size_t)bh * S_LEN * HDIM;
  const u16* Vp = Vtb + (size_t)bh * HDIM * S_LEN;
  u16* Pw = Plds[w];
  attn_strip(Qp, Kp, Vp, out, b, h, x * 64, w, tid, lane, x + 1, Kd, Vd, Pw);
  attn_strip(Qp, Kp, Vp, out, b, h, (31 - x) * 64, w, tid, lane, 32 - x, Kd, Vd, Pw);
}

extern "C" void kernel_launch(void* const* d_in, const int* in_sizes, int n_in,
                              void* d_out, int out_size, void* d_ws, size_t ws_size,
                              hipStream_t stream) {
  const float* x  = (const float*)d_in[0];
  const float* Wq = (const float*)d_in[1];
  const float* Wk = (const float*)d_in[2];
  const float* Wv = (const float*)d_in[3];
  float* out = (float*)d_out;

  u16* ws  = (u16*)d_ws;
  u16* xb  = ws;                    // 8192*1024
  u16* wqt = xb + 8388608;          // 3 x 1024*1024 contiguous
  u16* Qb  = wqt + 3145728;         // Q,K each [B,H,S,HD]
  u16* Kb  = Qb + 8388608;
  u16* Vtb = Kb + 8388608;          // [B,H,HD,S] written directly by k_gemm

  const float qscale = 0.125f * 1.44269504088896f;  // 1/sqrt(64) * log2(e)

  k_cvt<<<8192, 256, 0, stream>>>(x, xb);
  k_wt3<<<dim3(32, 32, 3), 256, 0, stream>>>(Wq, Wk, Wv, wqt);
  k_gemm<<<dim3(24, 64), 256, 0, stream>>>(xb, wqt, Qb, Vtb, qscale);
  k_attn<<<1024, 256, 0, stream>>>(Qb, Kb, Vtb, out);
}

// Round 14
// 132.748 us; speedup vs baseline: 5.0730x; 1.0497x over previous
//
#include <hip/hip_runtime.h>

typedef unsigned short u16;
typedef unsigned int u32;
typedef __bf16 bf16_t;
typedef bf16_t bf16x8 __attribute__((ext_vector_type(8)));
typedef bf16_t bf16x4_t __attribute__((ext_vector_type(4)));
typedef float f32x4 __attribute__((ext_vector_type(4)));
typedef unsigned short ushort8_t __attribute__((ext_vector_type(8)));

#define S_LEN 2048
#define DM 1024
#define NH 16
#define HDIM 64
#define PSTR 80   // attn P row stride in u16
#define TSTR 136  // epilogue-transpose LDS row stride in u16

// ---- helpers ----
__device__ __forceinline__ u16 f2b(float f) {
  u32 u = __builtin_bit_cast(u32, f);
  u32 r = (u + 0x7FFFu + ((u >> 16) & 1u)) >> 16;  // RNE
  return (u16)r;
}

__device__ __forceinline__ void gload16(const void* g, void* l) {
  __builtin_amdgcn_global_load_lds((const __attribute__((address_space(1))) void*)g,
                                   (__attribute__((address_space(3))) void*)l,
                                   16, 0, 0);
}

__device__ __forceinline__ bf16x8 ld_bf8(const u16* p) {
  return *reinterpret_cast<const bf16x8*>(p);
}

// ---- [R][64]-u16 tile staging (128B rows -> XOR swizzle is load-bearing, G4):
// pre-swizzled SOURCE column, linear LDS dest (rule #21); read with same XOR. ----
__device__ __forceinline__ void stage_rows64(const u16* __restrict__ base, int stride,
                                             u16* __restrict__ dst, int tid, int nchunk) {
#pragma unroll
  for (int i = 0; i < 4; ++i) {
    if (i < nchunk) {
      int ci = i * 256 + tid;
      int row = ci >> 3, col = ci & 7;
      gload16(base + (size_t)row * stride + ((col ^ (row & 7)) << 3), dst + ci * 8);
    }
  }
}
__device__ __forceinline__ void stage_tile256(const u16* __restrict__ base, int stride,
                                              u16* __restrict__ dst, int tid) {
  stage_rows64(base, stride, dst, tid, 2);
}
__device__ __forceinline__ bf16x8 ld_swz64(const u16* lds, int row, int chunk) {
  return ld_bf8(lds + row * 64 + ((chunk ^ (row & 7)) << 3));
}

// ---- kernel 1: x f32 -> bf16 ----
__global__ __launch_bounds__(256) void k_cvt(const float* __restrict__ in, u16* __restrict__ out) {
  int i = (blockIdx.x * 256 + threadIdx.x) * 4;
  float4 v = *reinterpret_cast<const float4*>(in + i);
  ushort4 o = make_ushort4(f2b(v.x), f2b(v.y), f2b(v.z), f2b(v.w));
  *reinterpret_cast<ushort4*>(out + i) = o;
}

// ---- kernel 2: all three W [K][N] f32 -> Wt [3*N][K] bf16 in one launch ----
__global__ __launch_bounds__(256) void k_wt3(const float* __restrict__ Wq, const float* __restrict__ Wk,
                                             const float* __restrict__ Wv, u16* __restrict__ Wt) {
  __shared__ float t[32][33];
  const float* W = (blockIdx.z == 0) ? Wq : (blockIdx.z == 1) ? Wk : Wv;
  u16* dst = Wt + (size_t)blockIdx.z * (DM * DM);
  int n0 = blockIdx.x * 32, k0 = blockIdx.y * 32;
  int tx = threadIdx.x & 31, ty = threadIdx.x >> 5;
#pragma unroll
  for (int i = 0; i < 32; i += 8)
    t[ty + i][tx] = W[(size_t)(k0 + ty + i) * DM + n0 + tx];
  __syncthreads();
#pragma unroll
  for (int i = 0; i < 32; i += 8)
    dst[(size_t)(n0 + ty + i) * DM + k0 + tx] = f2b(t[tx][ty + i]);
}

// ---- GEMM core: BK=64, 16 K-iters (half the barrier-drain events of BK=32),
// single buffer, swizzled [128][64] tiles. ks-split keeps live regs ~124.
// TRANSPOSED: mfma(bfr, af) so thread's 4 accs contiguous in n. ----
template <bool TRANSPOSED>
__device__ __forceinline__ void gemm_loop(const u16* __restrict__ Ag, const u16* __restrict__ Bg,
                                          u16* __restrict__ At, u16* __restrict__ Bt,
                                          f32x4 (&acc)[4][4], int tid, int l15, int lg,
                                          int wm, int wn) {
  for (int kt = 0; kt < 16; ++kt) {
    int kk = kt * 64;
    stage_rows64(Ag + kk, DM, At, tid, 4);
    stage_rows64(Bg + kk, DM, Bt, tid, 4);
    __syncthreads();
#pragma unroll
    for (int ks = 0; ks < 2; ++ks) {
      bf16x8 af[4], bfr[4];
#pragma unroll
      for (int mi = 0; mi < 4; ++mi)
        af[mi] = ld_swz64(At, wm * 64 + mi * 16 + l15, ks * 4 + lg);
#pragma unroll
      for (int ni = 0; ni < 4; ++ni)
        bfr[ni] = ld_swz64(Bt, wn * 64 + ni * 16 + l15, ks * 4 + lg);
#pragma unroll
      for (int mi = 0; mi < 4; ++mi)
#pragma unroll
        for (int ni = 0; ni < 4; ++ni) {
          if (TRANSPOSED)
            acc[mi][ni] = __builtin_amdgcn_mfma_f32_16x16x32_bf16(bfr[ni], af[mi], acc[mi][ni], 0, 0, 0);
          else
            acc[mi][ni] = __builtin_amdgcn_mfma_f32_16x16x32_bf16(af[mi], bfr[ni], acc[mi][ni], 0, 0, 0);
        }
    }
    __syncthreads();
  }
}

// ---- kernel 3: fused QKV GEMM, 128x128 tile, BK=64, 4 waves, 2D natural grid.
// __launch_bounds__(256,3) (R11's proven best). One-pass epilogue (R13's 2-pass
// cost ~8us). Staging 32KB union epilogue 34.8KB -> same 4-block LDS ceiling. ----
__global__ __launch_bounds__(256, 3) void k_gemm(const u16* __restrict__ Xb, const u16* __restrict__ Wt_all,
                                                 u16* __restrict__ Out_all, u16* __restrict__ Vt,
                                                 float qscale) {
  __shared__ __attribute__((aligned(16))) u16 smem[128 * TSTR];  // 34.8 KB (staging 32 KB / T 34.8 KB)
  u16* At = smem;           // 128x64
  u16* Bt = smem + 8192;    // 128x64
  int bx = blockIdx.x, by = blockIdx.y;
  int n0g = bx * 128, m0 = by * 128;
  int which = n0g >> 10;              // uniform per block (128 | 1024)
  int n0 = n0g & 1023;
  int tid = threadIdx.x;
  int lane = tid & 63, w = tid >> 6;
  int l15 = lane & 15, lg = lane >> 4;
  int wm = w >> 1, wn = w & 1;        // 2x2 waves, wave tile 64x64

  const u16* Ag = Xb + (size_t)m0 * DM;
  const u16* Bg = Wt_all + (size_t)n0g * DM;

  f32x4 acc[4][4] = {};
  u16* T = smem;
  int b = m0 >> 11, s0 = m0 & 2047;
  int base_h = n0 >> 6;

  if (which < 2) {
    gemm_loop<true>(Ag, Bg, At, Bt, acc, tid, l15, lg, wm, wn);
    // Q/K: thread holds 4 contiguous n at fixed m=l15 -> LDS [m][n] tile via b64
    float scale = (which == 0) ? qscale : 1.0f;
    u16* Out = Out_all + (size_t)which * (size_t)(4 * NH * S_LEN * HDIM);
#pragma unroll
    for (int mi = 0; mi < 4; ++mi) {
#pragma unroll
      for (int ni = 0; ni < 4; ++ni) {
        ushort4 w4 = make_ushort4(f2b(acc[mi][ni][0] * scale), f2b(acc[mi][ni][1] * scale),
                                  f2b(acc[mi][ni][2] * scale), f2b(acc[mi][ni][3] * scale));
        *reinterpret_cast<ushort4*>(T + (wm * 64 + mi * 16 + l15) * TSTR +
                                    wn * 64 + ni * 16 + lg * 4) = w4;
      }
    }
    __syncthreads();
#pragma unroll
    for (int pass = 0; pass < 8; ++pass) {
      int row = pass * 16 + (tid >> 4);     // m_local (s offset)
      int col = (tid & 15) * 8;             // n_local chunk (within one head)
      ushort8_t v = *reinterpret_cast<const ushort8_t*>(T + row * TSTR + col);
      int h = base_h + (col >> 6), hd = col & 63;
      *reinterpret_cast<ushort8_t*>(Out + ((size_t)(b * NH + h) * S_LEN + s0 + row) * HDIM + hd) = v;
    }
  } else {
    gemm_loop<false>(Ag, Bg, At, Bt, acc, tid, l15, lg, wm, wn);
    // V: thread holds 4 contiguous m at fixed n=l15 -> LDS [n][m] tile via b64
#pragma unroll
    for (int mi = 0; mi < 4; ++mi) {
#pragma unroll
      for (int ni = 0; ni < 4; ++ni) {
        ushort4 w4 = make_ushort4(f2b(acc[mi][ni][0]), f2b(acc[mi][ni][1]),
                                  f2b(acc[mi][ni][2]), f2b(acc[mi][ni][3]));
        *reinterpret_cast<ushort4*>(T + (wn * 64 + ni * 16 + l15) * TSTR +
                                    wm * 64 + mi * 16 + lg * 4) = w4;
      }
    }
    __syncthreads();
#pragma unroll
    for (int pass = 0; pass < 8; ++pass) {
      int row = pass * 16 + (tid >> 4);     // n_local (hd)
      int col = (tid & 15) * 8;             // m_local chunk (s offset)
      ushort8_t v = *reinterpret_cast<const ushort8_t*>(T + row * TSTR + col);
      int h = base_h + (row >> 6), hd = row & 63;
      *reinterpret_cast<ushort8_t*>(Vt + ((size_t)((b * NH + h) * HDIM + hd)) * S_LEN + s0 + col) = v;
    }
  }
}

// ---- block-cooperative flash strip: 4 waves, same head, lockstep K-tiles.
// K double-buffered (staged 1 ahead), V single-buffered. Counted waits only.
// Static-exponent softmax: p = exp2(s) raw (normalization cancels in o/ls). ----
__device__ __forceinline__ void attn_strip(const u16* __restrict__ Qp, const u16* __restrict__ Kp,
                                           const u16* __restrict__ Vp, float* __restrict__ out,
                                           int b, int h, int qbase, int w, int tid, int lane, int nt,
                                           u16 (*Kd)[64 * 64], u16* __restrict__ Vd,
                                           u16* __restrict__ Pw) {
  int l15 = lane & 15, lg = lane >> 4;
  int qrow = qbase + w * 16;
  bf16x8 qf0 = ld_bf8(Qp + (size_t)(qrow + l15) * HDIM + lg * 8);
  bf16x8 qf1 = ld_bf8(Qp + (size_t)(qrow + l15) * HDIM + 32 + lg * 8);
  f32x4 o[4] = {};
  float ls = 0.f;
  int qa = qrow + l15;

  stage_tile256(Kp, HDIM, Kd[0], tid);
  asm volatile("s_waitcnt vmcnt(0)" ::: "memory");
  __builtin_amdgcn_sched_barrier(0);
  __builtin_amdgcn_s_barrier();
  __builtin_amdgcn_sched_barrier(0);

  for (int kt = 0; kt < nt; ++kt) {
    int k0 = kt * 64;
    int cur = kt & 1;
    bool pre = (kt + 1 < nt);
    stage_tile256(Vp + k0, S_LEN, Vd, tid);
    if (pre) stage_tile256(Kp + (size_t)(k0 + 64) * HDIM, HDIM, Kd[cur ^ 1], tid);

    if (pre) asm volatile("s_waitcnt vmcnt(4)" ::: "memory");
    else     asm volatile("s_waitcnt vmcnt(2)" ::: "memory");
    __builtin_amdgcn_sched_barrier(0);
    __builtin_amdgcn_s_barrier();
    __builtin_amdgcn_sched_barrier(0);

    f32x4 sc[4];
    __builtin_amdgcn_s_setprio(1);
#pragma unroll
    for (int kb = 0; kb < 4; ++kb) {
      bf16x8 kf0 = ld_swz64(Kd[cur], kb * 16 + l15, lg);
      bf16x8 kf1 = ld_swz64(Kd[cur], kb * 16 + l15, 4 + lg);
      f32x4 z = {};
      z = __builtin_amdgcn_mfma_f32_16x16x32_bf16(kf0, qf0, z, 0, 0, 0);
      sc[kb] = __builtin_amdgcn_mfma_f32_16x16x32_bf16(kf1, qf1, sc[kb] = z, 0, 0, 0);
    }
    __builtin_amdgcn_s_setprio(0);

    if (kt == nt - 1) {
#pragma unroll
      for (int kb = 0; kb < 4; ++kb) {
        bf16x4_t pw;
#pragma unroll
        for (int r = 0; r < 4; ++r) {
          int key = k0 + kb * 16 + lg * 4 + r;
          float e = __builtin_amdgcn_exp2f(sc[kb][r]);
          e = (key > qa) ? 0.f : e;
          ls += e;
          pw[r] = (bf16_t)e;
        }
        *reinterpret_cast<bf16x4_t*>(Pw + l15 * PSTR + kb * 16 + lg * 4) = pw;
      }
    } else {
#pragma unroll
      for (int kb = 0; kb < 4; ++kb) {
        bf16x4_t pw;
#pragma unroll
        for (int r = 0; r < 4; ++r) {
          float e = __builtin_amdgcn_exp2f(sc[kb][r]);
          ls += e;
          pw[r] = (bf16_t)e;
        }
        *reinterpret_cast<bf16x4_t*>(Pw + l15 * PSTR + kb * 16 + lg * 4) = pw;
      }
    }
    asm volatile("" ::: "memory");
    bf16x8 pf0 = ld_bf8(Pw + l15 * PSTR + lg * 8);
    bf16x8 pf1 = ld_bf8(Pw + l15 * PSTR + 32 + lg * 8);

    if (pre) asm volatile("s_waitcnt vmcnt(2) lgkmcnt(0)" ::: "memory");
    else     asm volatile("s_waitcnt vmcnt(0) lgkmcnt(0)" ::: "memory");
    __builtin_amdgcn_sched_barrier(0);
    __builtin_amdgcn_s_barrier();
    __builtin_amdgcn_sched_barrier(0);

    __builtin_amdgcn_s_setprio(1);
#pragma unroll
    for (int n = 0; n < 4; ++n) {
      bf16x8 vf0 = ld_swz64(Vd, n * 16 + l15, lg);
      bf16x8 vf1 = ld_swz64(Vd, n * 16 + l15, 4 + lg);
      o[n] = __builtin_amdgcn_mfma_f32_16x16x32_bf16(pf0, vf0, o[n], 0, 0, 0);
      o[n] = __builtin_amdgcn_mfma_f32_16x16x32_bf16(pf1, vf1, o[n], 0, 0, 0);
    }
    __builtin_amdgcn_s_setprio(0);

    __builtin_amdgcn_sched_barrier(0);
    __builtin_amdgcn_s_barrier();
    __builtin_amdgcn_sched_barrier(0);
  }

  ls += __shfl_xor(ls, 16);
  ls += __shfl_xor(ls, 32);
  float l0 = __shfl(ls, lg * 4 + 0);
  float l1 = __shfl(ls, lg * 4 + 1);
  float l2 = __shfl(ls, lg * 4 + 2);
  float l3 = __shfl(ls, lg * 4 + 3);
  float lsr[4] = {l0, l1, l2, l3};
#pragma unroll
  for (int r = 0; r < 4; ++r) {
    float inv = 1.f / lsr[r];
    int row = qrow + lg * 4 + r;
#pragma unroll
    for (int n = 0; n < 4; ++n)
      out[((size_t)b * S_LEN + row) * DM + h * HDIM + n * 16 + l15] = o[n][r] * inv;
  }
}

// ---- kernel 5: causal flash attention ----
__global__ __launch_bounds__(256, 4) void k_attn(const u16* __restrict__ Qb, const u16* __restrict__ Kb,
                                                 const u16* __restrict__ Vtb, float* __restrict__ out) {
  __shared__ u16 Kd[2][64 * 64];
  __shared__ u16 Vd[64 * 64];
  __shared__ u16 Plds[4][16 * PSTR];
  int j = blockIdx.x;
  int m = j >> 3;
  int x = m & 15;
  int bh = (j & 7) + 8 * (m >> 4);
  int tid = threadIdx.x, lane = tid & 63, w = tid >> 6;
  int b = bh >> 4, h = bh & 15;
  const u16* Qp = Qb + (size_t)bh * S_LEN * HDIM;
  const u16* Kp = Kb + (size_t)bh * S_LEN * HDIM;
  const u16* Vp = Vtb + (size_t)bh * HDIM * S_LEN;
  u16* Pw = Plds[w];
  attn_strip(Qp, Kp, Vp, out, b, h, x * 64, w, tid, lane, x + 1, Kd, Vd, Pw);
  attn_strip(Qp, Kp, Vp, out, b, h, (31 - x) * 64, w, tid, lane, 32 - x, Kd, Vd, Pw);
}

extern "C" void kernel_launch(void* const* d_in, const int* in_sizes, int n_in,
                              void* d_out, int out_size, void* d_ws, size_t ws_size,
                              hipStream_t stream) {
  const float* x  = (const float*)d_in[0];
  const float* Wq = (const float*)d_in[1];
  const float* Wk = (const float*)d_in[2];
  const float* Wv = (const float*)d_in[3];
  float* out = (float*)d_out;

  u16* ws  = (u16*)d_ws;
  u16* xb  = ws;                    // 8192*1024
  u16* wqt = xb + 8388608;          // 3 x 1024*1024 contiguous
  u16* Qb  = wqt + 3145728;         // Q,K each [B,H,S,HD]
  u16* Kb  = Qb + 8388608;
  u16* Vtb = Kb + 8388608;          // [B,H,HD,S] written directly by k_gemm

  const float qscale = 0.125f * 1.44269504088896f;  // 1/sqrt(64) * log2(e)

  k_cvt<<<8192, 256, 0, stream>>>(x, xb);
  k_wt3<<<dim3(32, 32, 3), 256, 0, stream>>>(Wq, Wk, Wv, wqt);
  k_gemm<<<dim3(24, 64), 256, 0, stream>>>(xb, wqt, Qb, Vtb, qscale);
  k_attn<<<1024, 256, 0, stream>>>(Qb, Kb, Vtb, out);
}

// Round 15
// 126.966 us; speedup vs baseline: 5.3041x; 1.0455x over previous
//
#include <hip/hip_runtime.h>

typedef unsigned short u16;
typedef unsigned int u32;
typedef __bf16 bf16_t;
typedef bf16_t bf16x8 __attribute__((ext_vector_type(8)));
typedef bf16_t bf16x4_t __attribute__((ext_vector_type(4)));
typedef float f32x4 __attribute__((ext_vector_type(4)));
typedef unsigned short ushort8_t __attribute__((ext_vector_type(8)));

#define S_LEN 2048
#define DM 1024
#define NH 16
#define HDIM 64
#define TSTR 136  // gemm epilogue-transpose LDS row stride in u16

// ---- helpers ----
__device__ __forceinline__ u16 f2b(float f) {
  u32 u = __builtin_bit_cast(u32, f);
  u32 r = (u + 0x7FFFu + ((u >> 16) & 1u)) >> 16;  // RNE
  return (u16)r;
}

__device__ __forceinline__ void gload16(const void* g, void* l) {
  __builtin_amdgcn_global_load_lds((const __attribute__((address_space(1))) void*)g,
                                   (__attribute__((address_space(3))) void*)l,
                                   16, 0, 0);
}

__device__ __forceinline__ bf16x8 ld_bf8(const u16* p) {
  return *reinterpret_cast<const bf16x8*>(p);
}

// ---- [R][64]-u16 tile staging (128B rows -> XOR swizzle load-bearing, G4):
// pre-swizzled SOURCE column, linear LDS dest (rule #21); read with same XOR. ----
__device__ __forceinline__ void stage_rows64(const u16* __restrict__ base, int stride,
                                             u16* __restrict__ dst, int tid, int nchunk) {
#pragma unroll
  for (int i = 0; i < 4; ++i) {
    if (i < nchunk) {
      int ci = i * 256 + tid;
      int row = ci >> 3, col = ci & 7;
      gload16(base + (size_t)row * stride + ((col ^ (row & 7)) << 3), dst + ci * 8);
    }
  }
}
__device__ __forceinline__ void stage_tile256(const u16* __restrict__ base, int stride,
                                              u16* __restrict__ dst, int tid) {
  stage_rows64(base, stride, dst, tid, 2);
}
__device__ __forceinline__ bf16x8 ld_swz64(const u16* lds, int row, int chunk) {
  return ld_bf8(lds + row * 64 + ((chunk ^ (row & 7)) << 3));
}

// ---- kernel 1: x f32 -> bf16 ----
__global__ __launch_bounds__(256) void k_cvt(const float* __restrict__ in, u16* __restrict__ out) {
  int i = (blockIdx.x * 256 + threadIdx.x) * 4;
  float4 v = *reinterpret_cast<const float4*>(in + i);
  ushort4 o = make_ushort4(f2b(v.x), f2b(v.y), f2b(v.z), f2b(v.w));
  *reinterpret_cast<ushort4*>(out + i) = o;
}

// ---- kernel 2: all three W [K][N] f32 -> Wt [3*N][K] bf16 in one launch ----
__global__ __launch_bounds__(256) void k_wt3(const float* __restrict__ Wq, const float* __restrict__ Wk,
                                             const float* __restrict__ Wv, u16* __restrict__ Wt) {
  __shared__ float t[32][33];
  const float* W = (blockIdx.z == 0) ? Wq : (blockIdx.z == 1) ? Wk : Wv;
  u16* dst = Wt + (size_t)blockIdx.z * (DM * DM);
  int n0 = blockIdx.x * 32, k0 = blockIdx.y * 32;
  int tx = threadIdx.x & 31, ty = threadIdx.x >> 5;
#pragma unroll
  for (int i = 0; i < 32; i += 8)
    t[ty + i][tx] = W[(size_t)(k0 + ty + i) * DM + n0 + tx];
  __syncthreads();
#pragma unroll
  for (int i = 0; i < 32; i += 8)
    dst[(size_t)(n0 + ty + i) * DM + k0 + tx] = f2b(t[tx][ty + i]);
}

// ---- GEMM core: BK=64, 16 K-iters, single buffer, swizzled [128][64] tiles. ----
template <bool TRANSPOSED>
__device__ __forceinline__ void gemm_loop(const u16* __restrict__ Ag, const u16* __restrict__ Bg,
                                          u16* __restrict__ At, u16* __restrict__ Bt,
                                          f32x4 (&acc)[4][4], int tid, int l15, int lg,
                                          int wm, int wn) {
  for (int kt = 0; kt < 16; ++kt) {
    int kk = kt * 64;
    stage_rows64(Ag + kk, DM, At, tid, 4);
    stage_rows64(Bg + kk, DM, Bt, tid, 4);
    __syncthreads();
#pragma unroll
    for (int ks = 0; ks < 2; ++ks) {
      bf16x8 af[4], bfr[4];
#pragma unroll
      for (int mi = 0; mi < 4; ++mi)
        af[mi] = ld_swz64(At, wm * 64 + mi * 16 + l15, ks * 4 + lg);
#pragma unroll
      for (int ni = 0; ni < 4; ++ni)
        bfr[ni] = ld_swz64(Bt, wn * 64 + ni * 16 + l15, ks * 4 + lg);
#pragma unroll
      for (int mi = 0; mi < 4; ++mi)
#pragma unroll
        for (int ni = 0; ni < 4; ++ni) {
          if (TRANSPOSED)
            acc[mi][ni] = __builtin_amdgcn_mfma_f32_16x16x32_bf16(bfr[ni], af[mi], acc[mi][ni], 0, 0, 0);
          else
            acc[mi][ni] = __builtin_amdgcn_mfma_f32_16x16x32_bf16(af[mi], bfr[ni], acc[mi][ni], 0, 0, 0);
        }
    }
    __syncthreads();
  }
}

// ---- kernel 3: fused QKV GEMM, 128x128 tile, BK=64, 4 waves, 2D natural grid. ----
__global__ __launch_bounds__(256, 3) void k_gemm(const u16* __restrict__ Xb, const u16* __restrict__ Wt_all,
                                                 u16* __restrict__ Out_all, u16* __restrict__ Vt,
                                                 float qscale) {
  __shared__ __attribute__((aligned(16))) u16 smem[128 * TSTR];  // 34.8 KB
  u16* At = smem;           // 128x64
  u16* Bt = smem + 8192;    // 128x64
  int bx = blockIdx.x, by = blockIdx.y;
  int n0g = bx * 128, m0 = by * 128;
  int which = n0g >> 10;              // uniform per block (128 | 1024)
  int n0 = n0g & 1023;
  int tid = threadIdx.x;
  int lane = tid & 63, w = tid >> 6;
  int l15 = lane & 15, lg = lane >> 4;
  int wm = w >> 1, wn = w & 1;        // 2x2 waves, wave tile 64x64

  const u16* Ag = Xb + (size_t)m0 * DM;
  const u16* Bg = Wt_all + (size_t)n0g * DM;

  f32x4 acc[4][4] = {};
  u16* T = smem;
  int b = m0 >> 11, s0 = m0 & 2047;
  int base_h = n0 >> 6;

  if (which < 2) {
    gemm_loop<true>(Ag, Bg, At, Bt, acc, tid, l15, lg, wm, wn);
    float scale = (which == 0) ? qscale : 1.0f;
    u16* Out = Out_all + (size_t)which * (size_t)(4 * NH * S_LEN * HDIM);
#pragma unroll
    for (int mi = 0; mi < 4; ++mi) {
#pragma unroll
      for (int ni = 0; ni < 4; ++ni) {
        ushort4 w4 = make_ushort4(f2b(acc[mi][ni][0] * scale), f2b(acc[mi][ni][1] * scale),
                                  f2b(acc[mi][ni][2] * scale), f2b(acc[mi][ni][3] * scale));
        *reinterpret_cast<ushort4*>(T + (wm * 64 + mi * 16 + l15) * TSTR +
                                    wn * 64 + ni * 16 + lg * 4) = w4;
      }
    }
    __syncthreads();
#pragma unroll
    for (int pass = 0; pass < 8; ++pass) {
      int row = pass * 16 + (tid >> 4);
      int col = (tid & 15) * 8;
      ushort8_t v = *reinterpret_cast<const ushort8_t*>(T + row * TSTR + col);
      int h = base_h + (col >> 6), hd = col & 63;
      *reinterpret_cast<ushort8_t*>(Out + ((size_t)(b * NH + h) * S_LEN + s0 + row) * HDIM + hd) = v;
    }
  } else {
    gemm_loop<false>(Ag, Bg, At, Bt, acc, tid, l15, lg, wm, wn);
#pragma unroll
    for (int mi = 0; mi < 4; ++mi) {
#pragma unroll
      for (int ni = 0; ni < 4; ++ni) {
        ushort4 w4 = make_ushort4(f2b(acc[mi][ni][0]), f2b(acc[mi][ni][1]),
                                  f2b(acc[mi][ni][2]), f2b(acc[mi][ni][3]));
        *reinterpret_cast<ushort4*>(T + (wn * 64 + ni * 16 + l15) * TSTR +
                                    wm * 64 + mi * 16 + lg * 4) = w4;
      }
    }
    __syncthreads();
#pragma unroll
    for (int pass = 0; pass < 8; ++pass) {
      int row = pass * 16 + (tid >> 4);
      int col = (tid & 15) * 8;
      ushort8_t v = *reinterpret_cast<const ushort8_t*>(T + row * TSTR + col);
      int h = base_h + (row >> 6), hd = row & 63;
      *reinterpret_cast<ushort8_t*>(Vt + ((size_t)((b * NH + h) * HDIM + hd)) * S_LEN + s0 + col) = v;
    }
  }
}

// ---- block-cooperative flash strip, 1-barrier schedule.
// K AND V double-buffered, both prefetched 1 tile ahead. Per tile:
//   vmcnt(0)            <- drains loads issued a FULL iteration ago (nearly free)
//   s_barrier           <- the only barrier: makes all waves' stages visible AND
//                          proves every wave finished compute on buf[(t+1)&1]
//   stage K/V(t+1) -> buf[(t+1)&1]   (safe: all waves >= t)
//   QK -> softmax(exp2 raw) -> P (per-wave [16][64] LDS, XOR-swz) -> PV
// Safety: a wave issuing stage(t+1) crossed barrier(t); barrier(t) required all
// waves to finish compute(t-1) on that buffer; cross-wave data visibility holds
// because every wave drained vmcnt(0) BEFORE the shared barrier. ----
__device__ __forceinline__ void attn_strip(const u16* __restrict__ Qp, const u16* __restrict__ Kp,
                                           const u16* __restrict__ Vp, float* __restrict__ out,
                                           int b, int h, int qbase, int w, int tid, int lane, int nt,
                                           u16 (*Kd)[64 * 64], u16 (*Vd)[64 * 64],
                                           u16* __restrict__ Pw) {
  int l15 = lane & 15, lg = lane >> 4;
  int qrow = qbase + w * 16;
  bf16x8 qf0 = ld_bf8(Qp + (size_t)(qrow + l15) * HDIM + lg * 8);
  bf16x8 qf1 = ld_bf8(Qp + (size_t)(qrow + l15) * HDIM + 32 + lg * 8);
  f32x4 o[4] = {};
  float ls = 0.f;
  int qa = qrow + l15;
  int psw = (l15 & 7) << 3;  // P-tile XOR swizzle (u16 units)

  // prologue: stage tile 0 (drained by first loop iteration's vmcnt(0))
  stage_tile256(Kp, HDIM, Kd[0], tid);
  stage_tile256(Vp, S_LEN, Vd[0], tid);

  for (int kt = 0; kt < nt; ++kt) {
    int k0 = kt * 64;
    int cur = kt & 1;
    asm volatile("s_waitcnt vmcnt(0)" ::: "memory");
    __builtin_amdgcn_sched_barrier(0);
    __builtin_amdgcn_s_barrier();
    __builtin_amdgcn_sched_barrier(0);
    if (kt + 1 < nt) {
      stage_tile256(Kp + (size_t)(k0 + 64) * HDIM, HDIM, Kd[cur ^ 1], tid);
      stage_tile256(Vp + k0 + 64, S_LEN, Vd[cur ^ 1], tid);
    }

    // QK^T (swapped): lane holds q=l15, keys kb*16 + lg*4 + r
    f32x4 sc[4];
    __builtin_amdgcn_s_setprio(1);
#pragma unroll
    for (int kb = 0; kb < 4; ++kb) {
      bf16x8 kf0 = ld_swz64(Kd[cur], kb * 16 + l15, lg);
      bf16x8 kf1 = ld_swz64(Kd[cur], kb * 16 + l15, 4 + lg);
      f32x4 z = {};
      z = __builtin_amdgcn_mfma_f32_16x16x32_bf16(kf0, qf0, z, 0, 0, 0);
      sc[kb] = __builtin_amdgcn_mfma_f32_16x16x32_bf16(kf1, qf1, sc[kb] = z, 0, 0, 0);
    }
    __builtin_amdgcn_s_setprio(0);

    // static-exponent softmax; P -> per-wave LDS [16][64], col XOR psw
    if (kt == nt - 1) {
#pragma unroll
      for (int kb = 0; kb < 4; ++kb) {
        bf16x4_t pw;
#pragma unroll
        for (int r = 0; r < 4; ++r) {
          int key = k0 + kb * 16 + lg * 4 + r;
          float e = __builtin_amdgcn_exp2f(sc[kb][r]);
          e = (key > qa) ? 0.f : e;
          ls += e;
          pw[r] = (bf16_t)e;
        }
        *reinterpret_cast<bf16x4_t*>(Pw + l15 * 64 + ((kb * 16 + lg * 4) ^ psw)) = pw;
      }
    } else {
#pragma unroll
      for (int kb = 0; kb < 4; ++kb) {
        bf16x4_t pw;
#pragma unroll
        for (int r = 0; r < 4; ++r) {
          float e = __builtin_amdgcn_exp2f(sc[kb][r]);
          ls += e;
          pw[r] = (bf16_t)e;
        }
        *reinterpret_cast<bf16x4_t*>(Pw + l15 * 64 + ((kb * 16 + lg * 4) ^ psw)) = pw;
      }
    }
    asm volatile("" ::: "memory");  // P write -> read order (per-wave, DS in-order)
    bf16x8 pf0 = ld_bf8(Pw + l15 * 64 + ((lg * 8) ^ psw));
    bf16x8 pf1 = ld_bf8(Pw + l15 * 64 + ((32 + lg * 8) ^ psw));

    __builtin_amdgcn_s_setprio(1);
#pragma unroll
    for (int n = 0; n < 4; ++n) {
      bf16x8 vf0 = ld_swz64(Vd[cur], n * 16 + l15, lg);
      bf16x8 vf1 = ld_swz64(Vd[cur], n * 16 + l15, 4 + lg);
      o[n] = __builtin_amdgcn_mfma_f32_16x16x32_bf16(pf0, vf0, o[n], 0, 0, 0);
      o[n] = __builtin_amdgcn_mfma_f32_16x16x32_bf16(pf1, vf1, o[n], 0, 0, 0);
    }
    __builtin_amdgcn_s_setprio(0);
  }

  ls += __shfl_xor(ls, 16);
  ls += __shfl_xor(ls, 32);
  float l0 = __shfl(ls, lg * 4 + 0);
  float l1 = __shfl(ls, lg * 4 + 1);
  float l2 = __shfl(ls, lg * 4 + 2);
  float l3 = __shfl(ls, lg * 4 + 3);
  float lsr[4] = {l0, l1, l2, l3};
#pragma unroll
  for (int r = 0; r < 4; ++r) {
    float inv = 1.f / lsr[r];
    int row = qrow + lg * 4 + r;
#pragma unroll
    for (int n = 0; n < 4; ++n)
      out[((size_t)b * S_LEN + row) * DM + h * HDIM + n * 16 + l15] = o[n][r] * inv;
  }
}

// ---- kernel 5: causal flash attention.
// LDS = Kd 16K + Vd 16K + P 8K = 40960 B -> 4 blocks/CU exactly. ----
__global__ __launch_bounds__(256, 4) void k_attn(const u16* __restrict__ Qb, const u16* __restrict__ Kb,
                                                 const u16* __restrict__ Vtb, float* __restrict__ out) {
  __shared__ u16 Kd[2][64 * 64];
  __shared__ u16 Vd[2][64 * 64];
  __shared__ u16 Plds[4][16 * 64];
  int j = blockIdx.x;
  int m = j >> 3;
  int x = m & 15;
  int bh = (j & 7) + 8 * (m >> 4);
  int tid = threadIdx.x, lane = tid & 63, w = tid >> 6;
  int b = bh >> 4, h = bh & 15;
  const u16* Qp = Qb + (size_t)bh * S_LEN * HDIM;
  const u16* Kp = Kb + (size_t)bh * S_LEN * HDIM;
  const u16* Vp = Vtb + (size_t)bh * HDIM * S_LEN;
  u16* Pw = Plds[w];
  attn_strip(Qp, Kp, Vp, out, b, h, x * 64, w, tid, lane, x + 1, Kd, Vd, Pw);
  attn_strip(Qp, Kp, Vp, out, b, h, (31 - x) * 64, w, tid, lane, 32 - x, Kd, Vd, Pw);
}

extern "C" void kernel_launch(void* const* d_in, const int* in_sizes, int n_in,
                              void* d_out, int out_size, void* d_ws, size_t ws_size,
                              hipStream_t stream) {
  const float* x  = (const float*)d_in[0];
  const float* Wq = (const float*)d_in[1];
  const float* Wk = (const float*)d_in[2];
  const float* Wv = (const float*)d_in[3];
  float* out = (float*)d_out;

  u16* ws  = (u16*)d_ws;
  u16* xb  = ws;                    // 8192*1024
  u16* wqt = xb + 8388608;          // 3 x 1024*1024 contiguous
  u16* Qb  = wqt + 3145728;         // Q,K each [B,H,S,HD]
  u16* Kb  = Qb + 8388608;
  u16* Vtb = Kb + 8388608;          // [B,H,HD,S] written directly by k_gemm

  const float qscale = 0.125f * 1.44269504088896f;  // 1/sqrt(64) * log2(e)

  k_cvt<<<8192, 256, 0, stream>>>(x, xb);
  k_wt3<<<dim3(32, 32, 3), 256, 0, stream>>>(Wq, Wk, Wv, wqt);
  k_gemm<<<dim3(24, 64), 256, 0, stream>>>(xb, wqt, Qb, Vtb, qscale);
  k_attn<<<1024, 256, 0, stream>>>(Qb, Kb, Vtb, out);
}